// Round 17
// baseline (241.206 us; speedup 1.0000x reference)
//
#include <hip/hip_runtime.h>

typedef unsigned short u16;
typedef _Float16 f16;
typedef float  f32x4  __attribute__((ext_vector_type(4)));
typedef unsigned short u16x4 __attribute__((ext_vector_type(4)));
typedef f16    f16x8  __attribute__((ext_vector_type(8)));

__device__ __forceinline__ u16 f2h(float f) {
  f16 h = (f16)f;                      // RTN-even via v_cvt_f16_f32
  return __builtin_bit_cast(u16, h);
}

// raw s_barrier with compiler memory fences (no vmcnt drain)
#define BARRIER()                          \
  do {                                     \
    asm volatile("" ::: "memory");         \
    __builtin_amdgcn_s_barrier();          \
    asm volatile("" ::: "memory");         \
  } while (0)

template <int N> __device__ __forceinline__ void vmwait() {
  if constexpr (N == 0)       asm volatile("s_waitcnt vmcnt(0)" ::: "memory");
  else if constexpr (N == 3)  asm volatile("s_waitcnt vmcnt(3)" ::: "memory");
  else if constexpr (N == 4)  asm volatile("s_waitcnt vmcnt(4)" ::: "memory");
  else if constexpr (N == 5)  asm volatile("s_waitcnt vmcnt(5)" ::: "memory");
  else if constexpr (N == 6)  asm volatile("s_waitcnt vmcnt(6)" ::: "memory");
  else if constexpr (N == 8)  asm volatile("s_waitcnt vmcnt(8)" ::: "memory");
  else if constexpr (N == 10) asm volatile("s_waitcnt vmcnt(10)" ::: "memory");
  else if constexpr (N == 12) asm volatile("s_waitcnt vmcnt(12)" ::: "memory");
}

#define GLL16(g, l)                                                              \
  __builtin_amdgcn_global_load_lds(                                              \
      (const __attribute__((address_space(1))) unsigned int*)(g),                \
      (__attribute__((address_space(3))) unsigned int*)(l), 16, 0, 0)

// ---------------- fused prep: fp16 casts of x/Wq/Wk + tiled Wv transpose -----
__global__ __launch_bounds__(256) void prep_kernel(
    const float* __restrict__ x, const float* __restrict__ Wq,
    const float* __restrict__ Wk, const float* __restrict__ Wv,
    u16* __restrict__ xf, u16* __restrict__ wq16,
    u16* __restrict__ wk16, u16* __restrict__ wvt16) {
  __shared__ float tlds[64][65];
  const int bid = blockIdx.x, tid = threadIdx.x;
  if (bid < 13440) {  // straight f32 -> fp16 casts, vectorized
    const float* src;
    u16* dst;
    int i;
    if (bid < 12288) { src = x;  dst = xf;   i = bid * 256 + tid; }
    else if (bid < 12864) { src = Wq; dst = wq16; i = (bid - 12288) * 256 + tid; }
    else { src = Wk; dst = wk16; i = (bid - 12864) * 256 + tid; }
    f32x4 v = ((const f32x4*)src)[i];
    u16x4 h;
#pragma unroll
    for (int j = 0; j < 4; ++j) h[j] = f2h(v[j]);
    ((u16x4*)dst)[i] = h;
  } else {  // Wv transpose: 144 blocks, 12x12 tiles of 64x64
    const int tb = bid - 13440;
    const int d0 = (tb / 12) * 64, h0 = (tb % 12) * 64;
    const int c = tid & 63, grp = tid >> 6;
#pragma unroll
    for (int r = 0; r < 16; ++r) {
      const int dd = grp * 16 + r;
      tlds[dd][c] = Wv[(size_t)(d0 + dd) * 768 + h0 + c];  // coalesced in h
    }
    __syncthreads();
#pragma unroll
    for (int r = 0; r < 16; ++r) {
      const int hh = grp * 16 + r;
      wvt16[(size_t)(h0 + hh) * 768 + d0 + c] = f2h(tlds[c][hh]);  // coalesced in d
    }
  }
}

// ---------------- GEMM body: C(BM x BN) = A * B^T  (fp16 MFMA) --------------
// BK=32, 4 waves (2x2; wave tile (BM/2) x (BN/2)), 16x16x32 f16 MFMA.
// DEPTH-deep counted-vmcnt pipeline; raw barriers (loads stay in flight).
// Bank swizzle: LDS chunk c of row r holds global k-chunk c ^ ((r>>1)&3).
// EPI: 0 = f32 store (+causal mask), 2 = fp16 store
// KROW: Keff = (ti+1)*BM (causal PV K-limit)
template <int EPI, int CAUSAL, int KROW, int BM, int BN, int DEPTH>
__device__ __forceinline__ void gemm_body(
    u16* __restrict__ lds,
    const u16* __restrict__ pA, const u16* __restrict__ pB,
    void* __restrict__ Cv, size_t cbase,
    int K, int lda, int ldb, int ldc, int ti, int tj) {
  constexpr int ASZ = BM * 32;
  constexpr int BSZ = BN * 32;
  u16* As = lds;                     // [DEPTH][ASZ]
  u16* Bs = lds + DEPTH * ASZ;       // [DEPTH][BSZ]

  const int t = threadIdx.x, w = t >> 6, l = t & 63;
  const int wr = w >> 1, wc = w & 1;
  const int lr = l & 15, lk = l >> 4;
  constexpr int MI = BM / 32;              // m-frags per wave
  constexpr int NI = BN / 32;              // n-frags per wave
  constexpr int LPS = BM / 64 + BN / 64;   // global_load_lds per stage

  // staging: thread t -> LDS row t>>2, chunk t&3; global k-chunk is XOR-swizzled
  const int srow = t >> 2;
  const int sk8 = ((t & 3) ^ ((srow >> 1) & 3)) * 8;
  // swizzled chunk offset for fragment reads (row-bits come only from lr)
  const int ck = ((lk ^ ((lr >> 1) & 3)) << 3);

  const int Keff = KROW ? (ti + 1) * BM : K;
  const int nsteps = Keff >> 5;

  auto stage = [&](int bu, int kk) {
    const int kb = kk * 32;
#pragma unroll
    for (int s = 0; s < BM / 64; ++s)
      GLL16(pA + (size_t)(ti * BM + s * 64 + srow) * lda + sk8 + kb,
            As + bu * ASZ + s * 2048 + w * 512);
#pragma unroll
    for (int s = 0; s < BN / 64; ++s)
      GLL16(pB + (size_t)(tj * BN + s * 64 + srow) * ldb + sk8 + kb,
            Bs + bu * BSZ + s * 2048 + w * 512);
  };

  f32x4 acc[MI][NI] = {};

  stage(0, 0);
  if constexpr (DEPTH == 3) { if (nsteps > 1) stage(1, 1); }
  for (int kk = 0; kk < nsteps; ++kk) {
    const int buf = kk % DEPTH;
    if constexpr (DEPTH == 2) {
      if (kk + 1 < nsteps) { stage((kk + 1) % 2, kk + 1); vmwait<LPS>(); }
      else vmwait<0>();
    } else {
      if (kk + 2 < nsteps) { stage((kk + 2) % 3, kk + 2); vmwait<2 * LPS>(); }
      else if (kk + 1 < nsteps) vmwait<LPS>();
      else vmwait<0>();
    }
    BARRIER();  // all waves' tile-k loads landed

    f16x8 ah[MI], bh[NI];
#pragma unroll
    for (int mi = 0; mi < MI; ++mi) {
      const int ae = buf * ASZ + (wr * (BM / 2) + mi * 16 + lr) * 32 + ck;
      ah[mi] = *(const f16x8*)&As[ae];
    }
#pragma unroll
    for (int ni = 0; ni < NI; ++ni) {
      const int be = buf * BSZ + (wc * (BN / 2) + ni * 16 + lr) * 32 + ck;
      bh[ni] = *(const f16x8*)&Bs[be];
    }
#pragma unroll
    for (int mi = 0; mi < MI; ++mi)
#pragma unroll
      for (int ni = 0; ni < NI; ++ni)
        acc[mi][ni] = __builtin_amdgcn_mfma_f32_16x16x32_f16(ah[mi], bh[ni], acc[mi][ni], 0, 0, 0);
    BARRIER();  // all waves done reading buf before its next overwrite issues
  }

  // epilogue: C/D layout col = lane&15, row = (lane>>4)*4 + reg  [m89-verified]
#pragma unroll
  for (int mi = 0; mi < MI; ++mi)
#pragma unroll
    for (int ni = 0; ni < NI; ++ni)
#pragma unroll
      for (int r = 0; r < 4; ++r) {
        const int row = ti * BM + wr * (BM / 2) + mi * 16 + lk * 4 + r;
        const int col = tj * BN + wc * (BN / 2) + ni * 16 + lr;
        float v = acc[mi][ni][r];
        if (CAUSAL && col > row) v = -1e30f;
        const size_t idx = cbase + (size_t)row * ldc + col;
        if (EPI == 0) ((float*)Cv)[idx] = v;
        else          ((u16*)Cv)[idx] = f2h(v);
      }
}

// ---------------- generic GEMM wrapper (XCD-chunk bijective remap, m204) ----
// Causal skip generalized to rectangular tiles: skip iff tile's first col
// exceeds tile's last row: tj*BN >= (ti+1)*BM.
template <int EPI, int CAUSAL, int BM, int BN, int DEPTH, int MINW>
__global__ __launch_bounds__(256, MINW) void gemm_k(
    const u16* __restrict__ A, long sAb, const u16* __restrict__ B, long sBb,
    void* __restrict__ Cv, long sCb,
    int K, int lda, int ldb, int ldc, int gx, int gy) {
  __shared__ __align__(16) u16 lds[DEPTH * (BM * 32 + BN * 32)];
  const int nwg = gridDim.x;
  const int orig = blockIdx.x;
  const int q8 = nwg >> 3, r8 = nwg & 7;
  const int xcd = orig & 7, pos = orig >> 3;
  const int wgid = (xcd < r8 ? xcd * (q8 + 1) : r8 * (q8 + 1) + (xcd - r8) * q8) + pos;
  const int tj = wgid % gx;
  const int rest = wgid / gx;
  const int ti = rest % gy;
  const int zb = rest / gy;
  if (CAUSAL && tj * BN >= (ti + 1) * BM) return;
  gemm_body<EPI, CAUSAL, 0, BM, BN, DEPTH>(
      lds, A + (size_t)zb * sAb, B + (size_t)zb * sBb,
      Cv, (size_t)zb * sCb, K, lda, ldb, ldc, ti, tj);
}

// ---------------- fused projection: q' + vt, 768 all-resident blocks --------
// r11 configuration (best measured): 2 jobs per block, 128x128 tiles, DEPTH=3
// (48KB LDS, 3/CU, exactly all-resident).
__global__ __launch_bounds__(256, 3) void proj_kernel(
    const u16* __restrict__ xf, const u16* __restrict__ mt16,
    const u16* __restrict__ wvt16,
    u16* __restrict__ qf, u16* __restrict__ vtf) {
  __shared__ __align__(16) u16 lds[3 * (4096 + 4096)];
  const int orig = blockIdx.x;
  const int wgid = (orig & 7) * 96 + (orig >> 3);  // bijective (grid == 768)
#pragma unroll
  for (int j = 0; j < 2; ++j) {
    const int job = wgid * 2 + j;
    const int sidx = job / 12, sub = job % 12;
    if (sub < 6) {
      gemm_body<2, 0, 0, 128, 128, 3>(lds, xf, mt16, qf, 0,
                                      768, 768, 768, 768, sidx, sub);
    } else {
      gemm_body<2, 0, 0, 128, 128, 3>(lds, wvt16, xf, vtf, 0,
                                      768, 768, 768, 16384, sub - 6, sidx);
    }
  }
}

// ---------------- PV: out = P * vt^T, 128x256 tiles + heavy/light interleave -
// Grid = 48*g (3 h-tiles x 16 ti x g batches), 48KB LDS, 2/CU.
__global__ __launch_bounds__(256, 2) void pv_kernel(
    const u16* __restrict__ P, long sPb,
    const u16* __restrict__ vt,
    float* __restrict__ out, long sOb) {
  __shared__ __align__(16) u16 lds[2 * (4096 + 8192)];
  const int orig = blockIdx.x;
  const int nwg = gridDim.x;                       // 48*g, divisible by 8
  const int wgid = (orig & 7) * (nwg >> 3) + (orig >> 3);  // bijective
  const int tj = wgid % 3;
  const int s = (wgid / 3) % 16;
  const int zb = wgid / 48;
  const int ti = (s & 1) ? (s >> 1) : (15 - (s >> 1));  // heavy/light mix
  gemm_body<0, 0, 1, 128, 256, 2>(
      lds, P + (size_t)zb * sPb, vt + (size_t)zb * 2048,
      out, (size_t)zb * sOb, 2048, 2048, 16384, 768, ti, tj);
}

// ---------------- causal row softmax: scores f32 -> P fp16 ----------------
__global__ __launch_bounds__(256) void softmax_kernel(const float* __restrict__ S,
                                                      u16* __restrict__ P,
                                                      long sSb, long sPb) {
  const int wid = blockIdx.x * 4 + (threadIdx.x >> 6);  // one wave per row
  const int l = threadIdx.x & 63;
  const int zb = wid >> 11;
  const int i = wid & 2047;
  const float* row = S + (size_t)zb * sSb + (size_t)i * 2048;
  u16* prow = P + (size_t)zb * sPb + (size_t)i * 2048;
  const int Tend = ((i >> 7) + 1) << 7;  // multiple of 128
  const int nch = (Tend + 255) >> 8;

  f32x4 vb[8];
  float mx = -3e38f;
  for (int c = 0; c < nch; ++c) {
    const int j = c * 256 + l * 4;
    f32x4 v;
    if (j < Tend) v = *(const f32x4*)(row + j);
    else { v[0] = v[1] = v[2] = v[3] = -3e38f; }
    vb[c] = v;
    mx = fmaxf(mx, fmaxf(fmaxf(v[0], v[1]), fmaxf(v[2], v[3])));
  }
#pragma unroll
  for (int s = 32; s; s >>= 1) mx = fmaxf(mx, __shfl_xor(mx, s));

  float sum = 0.f;
  for (int c = 0; c < nch; ++c) {
    f32x4 v = vb[c];
#pragma unroll
    for (int j = 0; j < 4; ++j) {
      float e = expf(v[j] - mx);  // -1e30/-3e38 -> 0
      v[j] = e;
      sum += e;
    }
    vb[c] = v;
  }
#pragma unroll
  for (int s = 32; s; s >>= 1) sum += __shfl_xor(sum, s);
  const float inv = 1.f / sum;

  for (int c = 0; c < nch; ++c) {
    const int j = c * 256 + l * 4;
    if (j < Tend) {
      f32x4 v = vb[c];
      u16x4 o;
#pragma unroll
      for (int q = 0; q < 4; ++q) o[q] = f2h(v[q] * inv);
      *(u16x4*)(prow + j) = o;
    }
  }
}

// ---------------- orchestration ----------------
extern "C" void kernel_launch(void* const* d_in, const int* in_sizes, int n_in,
                              void* d_out, int out_size, void* d_ws, size_t ws_size,
                              hipStream_t stream) {
  const float* x  = (const float*)d_in[0];
  const float* Wq = (const float*)d_in[1];
  const float* Wk = (const float*)d_in[2];
  const float* Wv = (const float*)d_in[3];
  float* out = (float*)d_out;

  const int S = 2048, D = 768;
  const size_t ND = (size_t)8 * S * D;        // 12.58M
  const size_t NW = (size_t)D * D;            // 589824

  char* ws = (char*)d_ws;
  size_t off = 0;
  auto alloc = [&](size_t bytes) { size_t o = off; off = (off + bytes + 255) & ~(size_t)255; return o; };

  u16* xf   = (u16*)(ws + alloc(ND * 2));
  u16* qf   = (u16*)(ws + alloc(ND * 2));
  u16* vtf  = (u16*)(ws + alloc(ND * 2));
  u16* wq16 = (u16*)(ws + alloc(NW * 2));
  u16* wk16 = (u16*)(ws + alloc(NW * 2));
  u16* wvt16= (u16*)(ws + alloc(NW * 2));
  u16* mt16 = (u16*)(ws + alloc(NW * 2));
  const size_t fixed = off;

  const size_t perBatch = (size_t)S * S * 4 + (size_t)S * S * 2 + 512;  // scores f32 + P fp16
  int g = 0;
  for (int cand = 8; cand >= 1; cand >>= 1)
    if (fixed + (size_t)cand * perBatch <= ws_size) { g = cand; break; }
  if (!g) return;

  float* sc = (float*)(ws + alloc((size_t)g * S * S * 4));
  u16*   P  = (u16*)(ws + alloc((size_t)g * S * S * 2));

  // fused prep: fp16 casts + tiled Wv transpose
  prep_kernel<<<13584, 256, 0, stream>>>(x, Wq, Wk, Wv, xf, wq16, wk16, wvt16);

  // Mt[e][d] = sum_h Wk[e][h] * Wq[d][h]   (= (Wq Wk^T)^T), fp16 out
  gemm_k<2, 0, 128, 64, 2, 4><<<72, 256, 0, stream>>>(
      wk16, 0, wq16, 0, mt16, 0, 768, 768, 768, 768, 12, 6);

  // fused q' + vt: 768 all-resident blocks (r11 config)
  proj_kernel<<<768, 256, 0, stream>>>(xf, mt16, wvt16, qf, vtf);

  for (int b0 = 0; b0 < 8; b0 += g) {
    // scores[b][i][j] = q'[b,i] . x[b,j]  (128x256 tiles, causal skip)
    gemm_k<0, 1, 128, 256, 2, 2><<<8 * 16 * g, 256, 0, stream>>>(
        qf + (size_t)b0 * S * D, (long)S * D,
        xf + (size_t)b0 * S * D, (long)S * D,
        sc, (long)S * S, 768, 768, 768, 2048, 8, 16);

    softmax_kernel<<<g * 512, 256, 0, stream>>>(sc, P, (long)S * S, (long)S * S);

    // out[b][i][h] = sum_{j<Tend} P[b][i][j] * vt[h][b*2048+j]  (128x256)
    pv_kernel<<<48 * g, 256, 0, stream>>>(
        P, (long)S * S, vtf + (size_t)b0 * S,
        out + (size_t)b0 * S * D, (long)S * D);
  }
}

// Round 18
// 224.942 us; speedup vs baseline: 1.0723x; 1.0723x over previous
//
#include <hip/hip_runtime.h>

typedef unsigned short u16;
typedef _Float16 f16;
typedef float  f32x4  __attribute__((ext_vector_type(4)));
typedef unsigned short u16x4 __attribute__((ext_vector_type(4)));
typedef f16    f16x8  __attribute__((ext_vector_type(8)));

__device__ __forceinline__ u16 f2h(float f) {
  f16 h = (f16)f;                      // RTN-even via v_cvt_f16_f32
  return __builtin_bit_cast(u16, h);
}

// raw s_barrier with compiler memory fences (no vmcnt drain)
#define BARRIER()                          \
  do {                                     \
    asm volatile("" ::: "memory");         \
    __builtin_amdgcn_s_barrier();          \
    asm volatile("" ::: "memory");         \
  } while (0)

template <int N> __device__ __forceinline__ void vmwait() {
  if constexpr (N == 0)       asm volatile("s_waitcnt vmcnt(0)" ::: "memory");
  else if constexpr (N == 3)  asm volatile("s_waitcnt vmcnt(3)" ::: "memory");
  else if constexpr (N == 4)  asm volatile("s_waitcnt vmcnt(4)" ::: "memory");
  else if constexpr (N == 5)  asm volatile("s_waitcnt vmcnt(5)" ::: "memory");
  else if constexpr (N == 6)  asm volatile("s_waitcnt vmcnt(6)" ::: "memory");
  else if constexpr (N == 8)  asm volatile("s_waitcnt vmcnt(8)" ::: "memory");
  else if constexpr (N == 10) asm volatile("s_waitcnt vmcnt(10)" ::: "memory");
  else if constexpr (N == 12) asm volatile("s_waitcnt vmcnt(12)" ::: "memory");
}

#define GLL16(g, l)                                                              \
  __builtin_amdgcn_global_load_lds(                                              \
      (const __attribute__((address_space(1))) unsigned int*)(g),                \
      (__attribute__((address_space(3))) unsigned int*)(l), 16, 0, 0)

// ---------------- fused prep: fp16 casts of x/Wq/Wk + tiled Wv transpose -----
__global__ __launch_bounds__(256) void prep_kernel(
    const float* __restrict__ x, const float* __restrict__ Wq,
    const float* __restrict__ Wk, const float* __restrict__ Wv,
    u16* __restrict__ xf, u16* __restrict__ wq16,
    u16* __restrict__ wk16, u16* __restrict__ wvt16) {
  __shared__ float tlds[64][65];
  const int bid = blockIdx.x, tid = threadIdx.x;
  if (bid < 13440) {  // straight f32 -> fp16 casts, vectorized
    const float* src;
    u16* dst;
    int i;
    if (bid < 12288) { src = x;  dst = xf;   i = bid * 256 + tid; }
    else if (bid < 12864) { src = Wq; dst = wq16; i = (bid - 12288) * 256 + tid; }
    else { src = Wk; dst = wk16; i = (bid - 12864) * 256 + tid; }
    f32x4 v = ((const f32x4*)src)[i];
    u16x4 h;
#pragma unroll
    for (int j = 0; j < 4; ++j) h[j] = f2h(v[j]);
    ((u16x4*)dst)[i] = h;
  } else {  // Wv transpose: 144 blocks, 12x12 tiles of 64x64
    const int tb = bid - 13440;
    const int d0 = (tb / 12) * 64, h0 = (tb % 12) * 64;
    const int c = tid & 63, grp = tid >> 6;
#pragma unroll
    for (int r = 0; r < 16; ++r) {
      const int dd = grp * 16 + r;
      tlds[dd][c] = Wv[(size_t)(d0 + dd) * 768 + h0 + c];  // coalesced in h
    }
    __syncthreads();
#pragma unroll
    for (int r = 0; r < 16; ++r) {
      const int hh = grp * 16 + r;
      wvt16[(size_t)(h0 + hh) * 768 + d0 + c] = f2h(tlds[c][hh]);  // coalesced in d
    }
  }
}

// ---------------- GEMM body: C(BM x BN) = A * B^T  (fp16 MFMA) --------------
// BK=32, 4 waves (2x2; wave tile (BM/2) x (BN/2)), 16x16x32 f16 MFMA.
// DEPTH-deep counted-vmcnt pipeline; raw barriers (loads stay in flight).
// Bank swizzle: LDS chunk c of row r holds global k-chunk c ^ ((r>>1)&3).
// EPI: 0 = f32 store (+causal mask), 2 = fp16 store
// KROW: Keff = (ti+1)*BM (causal PV K-limit)
template <int EPI, int CAUSAL, int KROW, int BM, int BN, int DEPTH>
__device__ __forceinline__ void gemm_body(
    u16* __restrict__ lds,
    const u16* __restrict__ pA, const u16* __restrict__ pB,
    void* __restrict__ Cv, size_t cbase,
    int K, int lda, int ldb, int ldc, int ti, int tj) {
  constexpr int ASZ = BM * 32;
  constexpr int BSZ = BN * 32;
  u16* As = lds;                     // [DEPTH][ASZ]
  u16* Bs = lds + DEPTH * ASZ;       // [DEPTH][BSZ]

  const int t = threadIdx.x, w = t >> 6, l = t & 63;
  const int wr = w >> 1, wc = w & 1;
  const int lr = l & 15, lk = l >> 4;
  constexpr int MI = BM / 32;              // m-frags per wave
  constexpr int NI = BN / 32;              // n-frags per wave
  constexpr int LPS = BM / 64 + BN / 64;   // global_load_lds per stage

  // staging: thread t -> LDS row t>>2, chunk t&3; global k-chunk is XOR-swizzled
  const int srow = t >> 2;
  const int sk8 = ((t & 3) ^ ((srow >> 1) & 3)) * 8;
  // swizzled chunk offset for fragment reads (row-bits come only from lr)
  const int ck = ((lk ^ ((lr >> 1) & 3)) << 3);

  const int Keff = KROW ? (ti + 1) * BM : K;
  const int nsteps = Keff >> 5;

  auto stage = [&](int bu, int kk) {
    const int kb = kk * 32;
#pragma unroll
    for (int s = 0; s < BM / 64; ++s)
      GLL16(pA + (size_t)(ti * BM + s * 64 + srow) * lda + sk8 + kb,
            As + bu * ASZ + s * 2048 + w * 512);
#pragma unroll
    for (int s = 0; s < BN / 64; ++s)
      GLL16(pB + (size_t)(tj * BN + s * 64 + srow) * ldb + sk8 + kb,
            Bs + bu * BSZ + s * 2048 + w * 512);
  };

  f32x4 acc[MI][NI] = {};

  stage(0, 0);
  if constexpr (DEPTH == 3) { if (nsteps > 1) stage(1, 1); }
  for (int kk = 0; kk < nsteps; ++kk) {
    const int buf = kk % DEPTH;
    if constexpr (DEPTH == 2) {
      if (kk + 1 < nsteps) { stage((kk + 1) % 2, kk + 1); vmwait<LPS>(); }
      else vmwait<0>();
    } else {
      if (kk + 2 < nsteps) { stage((kk + 2) % 3, kk + 2); vmwait<2 * LPS>(); }
      else if (kk + 1 < nsteps) vmwait<LPS>();
      else vmwait<0>();
    }
    BARRIER();  // all waves' tile-k loads landed

    f16x8 ah[MI], bh[NI];
#pragma unroll
    for (int mi = 0; mi < MI; ++mi) {
      const int ae = buf * ASZ + (wr * (BM / 2) + mi * 16 + lr) * 32 + ck;
      ah[mi] = *(const f16x8*)&As[ae];
    }
#pragma unroll
    for (int ni = 0; ni < NI; ++ni) {
      const int be = buf * BSZ + (wc * (BN / 2) + ni * 16 + lr) * 32 + ck;
      bh[ni] = *(const f16x8*)&Bs[be];
    }
#pragma unroll
    for (int mi = 0; mi < MI; ++mi)
#pragma unroll
      for (int ni = 0; ni < NI; ++ni)
        acc[mi][ni] = __builtin_amdgcn_mfma_f32_16x16x32_f16(ah[mi], bh[ni], acc[mi][ni], 0, 0, 0);
    BARRIER();  // all waves done reading buf before its next overwrite issues
  }

  // epilogue: C/D layout col = lane&15, row = (lane>>4)*4 + reg  [m89-verified]
#pragma unroll
  for (int mi = 0; mi < MI; ++mi)
#pragma unroll
    for (int ni = 0; ni < NI; ++ni)
#pragma unroll
      for (int r = 0; r < 4; ++r) {
        const int row = ti * BM + wr * (BM / 2) + mi * 16 + lk * 4 + r;
        const int col = tj * BN + wc * (BN / 2) + ni * 16 + lr;
        float v = acc[mi][ni][r];
        if (CAUSAL && col > row) v = -1e30f;
        const size_t idx = cbase + (size_t)row * ldc + col;
        if (EPI == 0) ((float*)Cv)[idx] = v;
        else          ((u16*)Cv)[idx] = f2h(v);
      }
}

// ---------------- generic GEMM wrapper (XCD-chunk bijective remap, m204) ----
template <int EPI, int CAUSAL, int BM, int BN, int DEPTH, int MINW>
__global__ __launch_bounds__(256, MINW) void gemm_k(
    const u16* __restrict__ A, long sAb, const u16* __restrict__ B, long sBb,
    void* __restrict__ Cv, long sCb,
    int K, int lda, int ldb, int ldc, int gx, int gy) {
  __shared__ __align__(16) u16 lds[DEPTH * (BM * 32 + BN * 32)];
  const int nwg = gridDim.x;
  const int orig = blockIdx.x;
  const int q8 = nwg >> 3, r8 = nwg & 7;
  const int xcd = orig & 7, pos = orig >> 3;
  const int wgid = (xcd < r8 ? xcd * (q8 + 1) : r8 * (q8 + 1) + (xcd - r8) * q8) + pos;
  const int tj = wgid % gx;
  const int rest = wgid / gx;
  const int ti = rest % gy;
  const int zb = rest / gy;
  if (CAUSAL && tj * BN >= (ti + 1) * BM) return;  // == tj>ti at BM==BN
  gemm_body<EPI, CAUSAL, 0, BM, BN, DEPTH>(
      lds, A + (size_t)zb * sAb, B + (size_t)zb * sBb,
      Cv, (size_t)zb * sCb, K, lda, ldb, ldc, ti, tj);
}

// ---------------- fused projection: q' + vt, 768 all-resident blocks --------
// Best measured config (r11/r14): 2 jobs per block, 128x128 tiles, DEPTH=3
// (48KB LDS, 3/CU, exactly all-resident).
__global__ __launch_bounds__(256, 3) void proj_kernel(
    const u16* __restrict__ xf, const u16* __restrict__ mt16,
    const u16* __restrict__ wvt16,
    u16* __restrict__ qf, u16* __restrict__ vtf) {
  __shared__ __align__(16) u16 lds[3 * (4096 + 4096)];
  const int orig = blockIdx.x;
  const int wgid = (orig & 7) * 96 + (orig >> 3);  // bijective (grid == 768)
#pragma unroll
  for (int j = 0; j < 2; ++j) {
    const int job = wgid * 2 + j;
    const int sidx = job / 12, sub = job % 12;
    if (sub < 6) {
      gemm_body<2, 0, 0, 128, 128, 3>(lds, xf, mt16, qf, 0,
                                      768, 768, 768, 768, sidx, sub);
    } else {
      gemm_body<2, 0, 0, 128, 128, 3>(lds, wvt16, xf, vtf, 0,
                                      768, 768, 768, 16384, sub - 6, sidx);
    }
  }
}

// ---------------- PV: out = P * vt^T, 128x128 D3 + heavy/light interleave ---
// Grid = 96*g; remap chunk derived from gridDim.x (bijective for any g).
__global__ __launch_bounds__(256, 3) void pv_kernel(
    const u16* __restrict__ P, long sPb,
    const u16* __restrict__ vt,
    float* __restrict__ out, long sOb) {
  __shared__ __align__(16) u16 lds[3 * (4096 + 4096)];
  const int orig = blockIdx.x;
  const int nwg = gridDim.x;                       // 96*g, divisible by 8
  const int wgid = (orig & 7) * (nwg >> 3) + (orig >> 3);  // bijective
  const int tj = wgid % 6;
  const int s = (wgid / 6) % 16;
  const int zb = wgid / 96;
  const int ti = (s & 1) ? (s >> 1) : (15 - (s >> 1));  // heavy/light mix
  gemm_body<0, 0, 1, 128, 128, 3>(
      lds, P + (size_t)zb * sPb, vt + (size_t)zb * 2048,
      out, (size_t)zb * sOb, 2048, 2048, 16384, 768, ti, tj);
}

// ---------------- causal row softmax: scores f32 -> P fp16 ----------------
__global__ __launch_bounds__(256) void softmax_kernel(const float* __restrict__ S,
                                                      u16* __restrict__ P,
                                                      long sSb, long sPb) {
  const int wid = blockIdx.x * 4 + (threadIdx.x >> 6);  // one wave per row
  const int l = threadIdx.x & 63;
  const int zb = wid >> 11;
  const int i = wid & 2047;
  const float* row = S + (size_t)zb * sSb + (size_t)i * 2048;
  u16* prow = P + (size_t)zb * sPb + (size_t)i * 2048;
  const int Tend = ((i >> 7) + 1) << 7;  // multiple of 128
  const int nch = (Tend + 255) >> 8;

  f32x4 vb[8];
  float mx = -3e38f;
  for (int c = 0; c < nch; ++c) {
    const int j = c * 256 + l * 4;
    f32x4 v;
    if (j < Tend) v = *(const f32x4*)(row + j);
    else { v[0] = v[1] = v[2] = v[3] = -3e38f; }
    vb[c] = v;
    mx = fmaxf(mx, fmaxf(fmaxf(v[0], v[1]), fmaxf(v[2], v[3])));
  }
#pragma unroll
  for (int s = 32; s; s >>= 1) mx = fmaxf(mx, __shfl_xor(mx, s));

  float sum = 0.f;
  for (int c = 0; c < nch; ++c) {
    f32x4 v = vb[c];
#pragma unroll
    for (int j = 0; j < 4; ++j) {
      float e = expf(v[j] - mx);  // -1e30/-3e38 -> 0
      v[j] = e;
      sum += e;
    }
    vb[c] = v;
  }
#pragma unroll
  for (int s = 32; s; s >>= 1) sum += __shfl_xor(sum, s);
  const float inv = 1.f / sum;

  for (int c = 0; c < nch; ++c) {
    const int j = c * 256 + l * 4;
    if (j < Tend) {
      f32x4 v = vb[c];
      u16x4 o;
#pragma unroll
      for (int q = 0; q < 4; ++q) o[q] = f2h(v[q] * inv);
      *(u16x4*)(prow + j) = o;
    }
  }
}

// ---------------- orchestration ----------------
extern "C" void kernel_launch(void* const* d_in, const int* in_sizes, int n_in,
                              void* d_out, int out_size, void* d_ws, size_t ws_size,
                              hipStream_t stream) {
  const float* x  = (const float*)d_in[0];
  const float* Wq = (const float*)d_in[1];
  const float* Wk = (const float*)d_in[2];
  const float* Wv = (const float*)d_in[3];
  float* out = (float*)d_out;

  const int S = 2048, D = 768;
  const size_t ND = (size_t)8 * S * D;        // 12.58M
  const size_t NW = (size_t)D * D;            // 589824

  char* ws = (char*)d_ws;
  size_t off = 0;
  auto alloc = [&](size_t bytes) { size_t o = off; off = (off + bytes + 255) & ~(size_t)255; return o; };

  u16* xf   = (u16*)(ws + alloc(ND * 2));
  u16* qf   = (u16*)(ws + alloc(ND * 2));
  u16* vtf  = (u16*)(ws + alloc(ND * 2));
  u16* wq16 = (u16*)(ws + alloc(NW * 2));
  u16* wk16 = (u16*)(ws + alloc(NW * 2));
  u16* wvt16= (u16*)(ws + alloc(NW * 2));
  u16* mt16 = (u16*)(ws + alloc(NW * 2));
  const size_t fixed = off;

  const size_t perBatch = (size_t)S * S * 4 + (size_t)S * S * 2 + 512;  // scores f32 + P fp16
  int g = 0;
  for (int cand = 8; cand >= 1; cand >>= 1)
    if (fixed + (size_t)cand * perBatch <= ws_size) { g = cand; break; }
  if (!g) return;

  float* sc = (float*)(ws + alloc((size_t)g * S * S * 4));
  u16*   P  = (u16*)(ws + alloc((size_t)g * S * S * 2));

  // fused prep: fp16 casts + tiled Wv transpose
  prep_kernel<<<13584, 256, 0, stream>>>(x, Wq, Wk, Wv, xf, wq16, wk16, wvt16);

  // Mt[e][d] = sum_h Wk[e][h] * Wq[d][h]   (= (Wq Wk^T)^T), fp16 out
  gemm_k<2, 0, 128, 64, 2, 4><<<72, 256, 0, stream>>>(
      wk16, 0, wq16, 0, mt16, 0, 768, 768, 768, 768, 12, 6);

  // fused q' + vt: 768 all-resident blocks
  proj_kernel<<<768, 256, 0, stream>>>(xf, mt16, wvt16, qf, vtf);

  for (int b0 = 0; b0 < 8; b0 += g) {
    // scores[b][i][j] = q'[b,i] . x[b,j]  (128x128 tiles, causal skip)
    gemm_k<0, 1, 128, 128, 2, 4><<<16 * 16 * g, 256, 0, stream>>>(
        qf + (size_t)b0 * S * D, (long)S * D,
        xf + (size_t)b0 * S * D, (long)S * D,
        sc, (long)S * S, 768, 768, 768, 2048, 16, 16);

    softmax_kernel<<<g * 512, 256, 0, stream>>>(sc, P, (long)S * S, (long)S * S);

    // out[b][i][h] = sum_{j<Tend} P[b][i][j] * vt[h][b*2048+j]
    pv_kernel<<<96 * g, 256, 0, stream>>>(
        P, (long)S * S, vtf + (size_t)b0 * S,
        out + (size_t)b0 * S * D, (long)S * D);
  }
}